// Round 2
// baseline (4948.576 us; speedup 1.0000x reference)
//
#include <hip/hip_runtime.h>
#include <hip/hip_bf16.h>

// Problem constants (from reference)
#define N_ENT    100000
#define N_REL    250000
#define N_TRIG   50000
#define N_ARGS   250000
#define ENT_DIM  288
#define REL_R    256
#define RTYPE_DIM 32
#define ROLE_DIM 256
#define ARG_DIM  576           // REL_R + RTYPE_DIM + ENT_DIM
#define OUT_DIM  544           // ENT_DIM + ROLE_DIM

// Kernel 1: out[t, 0:288] = ent_embeds[trig_ent_id[t]];  out[t, 288:544] = 0.
// grid = N_TRIG, block = 256
__global__ void __launch_bounds__(256)
k_init(const float* __restrict__ ent, const int* __restrict__ trig_ent,
       float* __restrict__ out)
{
    const int t   = blockIdx.x;
    const int tid = threadIdx.x;
    const int e   = trig_ent[t];
    const float* src = ent + (size_t)e * ENT_DIM;
    float*       dst = out + (size_t)t * OUT_DIM;
    dst[tid] = src[tid];                                   // cols 0..255
    if (tid < ENT_DIM - 256) dst[256 + tid] = src[256 + tid]; // cols 256..287
    dst[ENT_DIM + tid] = 0.f;                              // cols 288..543
}

// Kernel 2: per-arg matvec y = x @ (is_in ? W_in : W_out), atomically
// accumulated per trigger directly into out[:, 288:544].
// grid = N_ARGS, block = 256 (1 output column per thread)
__global__ void __launch_bounds__(256)
k_arg(const float* __restrict__ ent,  const float* __restrict__ rel,
      const float* __restrict__ rtab, const float* __restrict__ W_in,
      const float* __restrict__ W_out,
      const int* __restrict__ rtype_ids, const int* __restrict__ arg_trig,
      const int* __restrict__ arg_rel,   const int* __restrict__ arg_ent,
      const int* __restrict__ arg_is_in, float* __restrict__ out)
{
    __shared__ float xs[ARG_DIM];

    const int a    = blockIdx.x;
    const int t    = threadIdx.x;
    const int r    = arg_rel[a];
    const int e    = arg_ent[a];
    const int tg   = arg_trig[a];
    const int isin = arg_is_in[a];
    const int rt   = rtype_ids[r];

    // Stage x = [rel(256) | rtype(32) | ent(288)] into LDS.
    xs[t] = rel[(size_t)r * REL_R + t];
    {
        int i = 256 + t;                       // 256..511
        if (i < 288) xs[i] = rtab[rt * RTYPE_DIM + (i - 256)];
        else         xs[i] = ent[(size_t)e * ENT_DIM + (i - 288)];
    }
    {
        int i = 512 + t;                       // 512..575
        if (i < ARG_DIM) xs[i] = ent[(size_t)e * ENT_DIM + (i - 288)];
    }
    __syncthreads();

    const float* __restrict__ W = isin ? W_in : W_out;
    float s = 0.f;
#pragma unroll 8
    for (int k = 0; k < ARG_DIM; ++k) {
        s += xs[k] * W[(size_t)k * ROLE_DIM + t];
    }
    atomicAdd(&out[(size_t)tg * OUT_DIM + ENT_DIM + t], s);
}

extern "C" void kernel_launch(void* const* d_in, const int* in_sizes, int n_in,
                              void* d_out, int out_size, void* d_ws, size_t ws_size,
                              hipStream_t stream)
{
    const float* ent      = (const float*)d_in[0];   // [N_ENT, 288]
    const float* rel      = (const float*)d_in[1];   // [N_REL, 256]
    const float* rtab     = (const float*)d_in[2];   // [201, 32]
    const float* W_in     = (const float*)d_in[3];   // [576, 256]
    const float* W_out    = (const float*)d_in[4];   // [576, 256]
    const int*  rtype_ids = (const int*)d_in[5];     // [N_REL]
    const int*  trig_ent  = (const int*)d_in[6];     // [N_TRIG]
    const int*  arg_trig  = (const int*)d_in[7];     // [N_ARGS]
    const int*  arg_rel   = (const int*)d_in[8];     // [N_ARGS]
    const int*  arg_ent   = (const int*)d_in[9];     // [N_ARGS]
    const int*  arg_is_in = (const int*)d_in[10];    // [N_ARGS]

    float* out = (float*)d_out;                      // [N_TRIG, 544] f32

    hipLaunchKernelGGL(k_init, dim3(N_TRIG), dim3(256), 0, stream,
                       ent, trig_ent, out);
    hipLaunchKernelGGL(k_arg, dim3(N_ARGS), dim3(256), 0, stream,
                       ent, rel, rtab, W_in, W_out,
                       rtype_ids, arg_trig, arg_rel, arg_ent, arg_is_in, out);
}

// Round 3
// 868.665 us; speedup vs baseline: 5.6968x; 5.6968x over previous
//
#include <hip/hip_runtime.h>
#include <hip/hip_bf16.h>
#include <stdint.h>

// Problem constants (from reference)
#define N_ENT    100000
#define N_REL    250000
#define N_TRIG   50000
#define N_ARGS   250000
#define ENT_DIM  288
#define REL_R    256
#define RTYPE_DIM 32
#define ROLE_DIM 256
#define ARG_DIM  576           // REL_R + RTYPE_DIM + ENT_DIM
#define OUT_DIM  544           // ENT_DIM + ROLE_DIM

// GEMM tiling
#define BM 64                  // args per block
#define BK 32                  // K chunk (one MFMA K-step)
#define NSTEP (ARG_DIM / BK)   // 18
#define LDP 40                 // padded K-stride in LDS (shorts): 80 B rows ->
                               // 16B-aligned b128 frags, <=2-way bank conflicts

typedef __attribute__((ext_vector_type(8))) short bf16x8;   // 8 bf16 (4 VGPRs)
typedef __attribute__((ext_vector_type(4))) float f32x4;    // MFMA acc

// f32 -> bf16 (round-to-nearest-even), bit-level
__device__ __forceinline__ short f2b(float f) {
    union { float f; uint32_t u; } v; v.f = f;
    uint32_t u = v.u;
    uint32_t r = (u + 0x7fffu + ((u >> 16) & 1u)) >> 16;
    return (short)r;
}

// Kernel 1: out[t, 0:288] = ent[trig_ent[t]];  out[t, 288:544] = 0.
__global__ void __launch_bounds__(256)
k_init(const float* __restrict__ ent, const int* __restrict__ trig_ent,
       float* __restrict__ out)
{
    const int t   = blockIdx.x;
    const int tid = threadIdx.x;
    const int e   = trig_ent[t];
    const float* src = ent + (size_t)e * ENT_DIM;
    float*       dst = out + (size_t)t * OUT_DIM;
    dst[tid] = src[tid];
    if (tid < ENT_DIM - 256) dst[256 + tid] = src[256 + tid];
    dst[ENT_DIM + tid] = 0.f;
}

// Kernel 2: convert+transpose W_in/W_out f32[576][256] -> Wb bf16[2][256][576]
// (per-column contiguous k, so GEMM B-staging reads are contiguous b128s)
__global__ void __launch_bounds__(256)
k_prep(const float* __restrict__ W_in, const float* __restrict__ W_out,
       short* __restrict__ Wb)
{
    const int idx = blockIdx.x * 256 + threadIdx.x;     // 0 .. 2*576*256-1
    const int w   = idx / (ARG_DIM * ROLE_DIM);
    const int rem = idx % (ARG_DIM * ROLE_DIM);
    const int k   = rem / ROLE_DIM;
    const int col = rem % ROLE_DIM;
    const float* src = (w == 0) ? W_in : W_out;
    Wb[((size_t)w * ROLE_DIM + col) * ARG_DIM + k] = f2b(src[k * ROLE_DIM + col]);
}

// Kernel 3: fused gather + bf16 MFMA GEMM + atomic segment-sum.
// Block: 256 threads (4 waves). M-tile = 64 args, N = 256 (wave w owns cols
// 64w..64w+63). K = 576 in 18 chunks of 32. Per-row W_in/W_out selection via
// masked double-MFMA into a single accumulator.
__global__ void __launch_bounds__(256)
k_gemm(const float* __restrict__ ent,  const float* __restrict__ rel,
       const float* __restrict__ rtab, const short* __restrict__ Wb,
       const int* __restrict__ rtype_ids, const int* __restrict__ arg_trig,
       const int* __restrict__ arg_rel,   const int* __restrict__ arg_ent,
       const int* __restrict__ arg_is_in, float* __restrict__ out)
{
    __shared__ short As[BM][LDP];        // A chunk: 64 rows x 32 k (padded)
    __shared__ short Bi[ROLE_DIM][LDP];  // W_in chunk: 256 cols x 32 k
    __shared__ short Bo[ROLE_DIM][LDP];  // W_out chunk
    __shared__ int s_rel[BM], s_ent[BM], s_rt[BM], s_trig[BM], s_mask[BM];

    const int tid = threadIdx.x;
    const int a0  = blockIdx.x * BM;

    // Per-arg metadata (mask: 1 = W_in, 0 = W_out, -1 = invalid row)
    if (tid < BM) {
        int a     = a0 + tid;
        int valid = (a < N_ARGS);
        int aa    = valid ? a : (N_ARGS - 1);
        int r     = arg_rel[aa];
        s_rel[tid]  = r;
        s_ent[tid]  = arg_ent[aa];
        s_rt[tid]   = rtype_ids[r];
        s_trig[tid] = arg_trig[aa];
        s_mask[tid] = valid ? arg_is_in[aa] : -1;
    }
    __syncthreads();

    const int lane  = tid & 63;
    const int wave  = tid >> 6;
    const int quad  = lane >> 4;
    const int l15   = lane & 15;
    const int nbase = wave * 64;

    // A-fragment row for m-tile m is m*16 + l15 -> per-lane scalar mask
    int rowmask[4];
#pragma unroll
    for (int m = 0; m < 4; ++m) rowmask[m] = s_mask[m * 16 + l15];

    f32x4 acc[4][4];
#pragma unroll
    for (int m = 0; m < 4; ++m)
#pragma unroll
        for (int n = 0; n < 4; ++n) acc[m][n] = (f32x4){0.f, 0.f, 0.f, 0.f};

    const bf16x8 zf = {0, 0, 0, 0, 0, 0, 0, 0};

    // A-staging coords: thread handles row = tid>>2, 8 consecutive k at
    // kq = (tid&3)*8  (two float4 global loads -> one 16B LDS store)
    const int srow = tid >> 2;
    const int skq  = (tid & 3) * 8;

    for (int s = 0; s < NSTEP; ++s) {
        __syncthreads();   // previous compute done before overwriting LDS

        // ---- stage A (gathered, f32 -> bf16) ----
        {
            const int k = s * BK + skq;   // global K index (region-uniform per s)
            const float* src;
            if (k < REL_R)
                src = rel + (size_t)s_rel[srow] * REL_R + k;
            else if (k < REL_R + RTYPE_DIM)
                src = rtab + s_rt[srow] * RTYPE_DIM + (k - REL_R);
            else
                src = ent + (size_t)s_ent[srow] * ENT_DIM + (k - REL_R - RTYPE_DIM);
            float4 v0 = *(const float4*)src;
            float4 v1 = *(const float4*)(src + 4);
            bf16x8 h;
            h[0] = f2b(v0.x); h[1] = f2b(v0.y); h[2] = f2b(v0.z); h[3] = f2b(v0.w);
            h[4] = f2b(v1.x); h[5] = f2b(v1.y); h[6] = f2b(v1.z); h[7] = f2b(v1.w);
            *(bf16x8*)&As[srow][skq] = h;
        }

        // ---- stage B (both W, bf16, col-major-k: contiguous 32 shorts) ----
        {
            const short* pin = Wb + (size_t)tid * ARG_DIM + s * BK;
            const short* pot = Wb + ((size_t)ROLE_DIM + tid) * ARG_DIM + s * BK;
#pragma unroll
            for (int j = 0; j < 4; ++j) {
                *(bf16x8*)&Bi[tid][j * 8] = *(const bf16x8*)(pin + j * 8);
                *(bf16x8*)&Bo[tid][j * 8] = *(const bf16x8*)(pot + j * 8);
            }
        }
        __syncthreads();

        // ---- fragments + masked double-MFMA ----
        bf16x8 a[4], bi[4], bo[4];
#pragma unroll
        for (int m = 0; m < 4; ++m)
            a[m] = *(const bf16x8*)&As[m * 16 + l15][quad * 8];
#pragma unroll
        for (int n = 0; n < 4; ++n) {
            bi[n] = *(const bf16x8*)&Bi[nbase + n * 16 + l15][quad * 8];
            bo[n] = *(const bf16x8*)&Bo[nbase + n * 16 + l15][quad * 8];
        }
#pragma unroll
        for (int m = 0; m < 4; ++m) {
            const bf16x8 ain = (rowmask[m] == 1) ? a[m] : zf;
            const bf16x8 aot = (rowmask[m] == 0) ? a[m] : zf;
#pragma unroll
            for (int n = 0; n < 4; ++n) {
                acc[m][n] = __builtin_amdgcn_mfma_f32_16x16x32_bf16(
                    ain, bi[n], acc[m][n], 0, 0, 0);
                acc[m][n] = __builtin_amdgcn_mfma_f32_16x16x32_bf16(
                    aot, bo[n], acc[m][n], 0, 0, 0);
            }
        }
    }

    // ---- epilogue: atomic segment-sum into out[:, 288:544] ----
    // C/D layout: col = lane&15, row = quad*4 + reg  [m89-verified]
#pragma unroll
    for (int m = 0; m < 4; ++m) {
#pragma unroll
        for (int r4 = 0; r4 < 4; ++r4) {
            const int row = m * 16 + quad * 4 + r4;
            if (s_mask[row] < 0) continue;           // padded row
            float* dst = out + (size_t)s_trig[row] * OUT_DIM + ENT_DIM;
#pragma unroll
            for (int n = 0; n < 4; ++n) {
                const int col = nbase + n * 16 + l15;
                atomicAdd(dst + col, acc[m][n][r4]);
            }
        }
    }
}

extern "C" void kernel_launch(void* const* d_in, const int* in_sizes, int n_in,
                              void* d_out, int out_size, void* d_ws, size_t ws_size,
                              hipStream_t stream)
{
    const float* ent      = (const float*)d_in[0];   // [N_ENT, 288]
    const float* rel      = (const float*)d_in[1];   // [N_REL, 256]
    const float* rtab     = (const float*)d_in[2];   // [201, 32]
    const float* W_in     = (const float*)d_in[3];   // [576, 256]
    const float* W_out    = (const float*)d_in[4];   // [576, 256]
    const int*  rtype_ids = (const int*)d_in[5];
    const int*  trig_ent  = (const int*)d_in[6];
    const int*  arg_trig  = (const int*)d_in[7];
    const int*  arg_rel   = (const int*)d_in[8];
    const int*  arg_ent   = (const int*)d_in[9];
    const int*  arg_is_in = (const int*)d_in[10];

    float* out = (float*)d_out;                      // [N_TRIG, 544] f32
    short* Wb  = (short*)d_ws;                       // [2][256][576] bf16, 576 KB

    hipLaunchKernelGGL(k_init, dim3(N_TRIG), dim3(256), 0, stream,
                       ent, trig_ent, out);
    hipLaunchKernelGGL(k_prep, dim3(2 * ARG_DIM * ROLE_DIM / 256), dim3(256), 0,
                       stream, W_in, W_out, Wb);
    hipLaunchKernelGGL(k_gemm, dim3((N_ARGS + BM - 1) / BM), dim3(256), 0, stream,
                       ent, rel, rtab, Wb,
                       rtype_ids, arg_trig, arg_rel, arg_ent, arg_is_in, out);
}